// Round 12
// baseline (1098.923 us; speedup 1.0000x reference)
//
#include <hip/hip_runtime.h>
#include <hip/hip_bf16.h>

// Problem constants (from reference)
#define NN   50000
#define EE   1600000
#define INC  128
#define HH   64
#define OUTC 40
#define ALPHA 0.8f
#define LN_EPS 1e-5f
#define CAP  128   // compact slots/node (ushort); max deg ~101 for Poisson(64)
#define CAPS 36    // slots per (node,XCD) sub-segment; deg/XCD ~ Poisson(8)
#define SUBW (8 * CAPS)   // 288 ushorts = 576 B per node
// h is stored pre-scaled by 2*log2(e) so tanh needs no per-edge multiply:
// tanh(x) = 1 - 2/(1 + 2^(KTANH*x)).  (R8 lesson: polynomial tanh approx
// is NOT safe here -- LN divides by sigma which can be ~sqrt(eps), so
// absolute tanh error amplifies ~300x. Keep the exact exp2 form.)
#define KTANH 2.8853900817779268f

typedef int v4i_t __attribute__((ext_vector_type(4)));
typedef _Float16 h8 __attribute__((ext_vector_type(8)));
typedef __fp16 hv2 __attribute__((ext_vector_type(2)));   // cvt_pkrtz's type
typedef float f32x4 __attribute__((ext_vector_type(4)));
typedef int i32x2 __attribute__((ext_vector_type(2)));
typedef int i32x4 __attribute__((ext_vector_type(4)));

__device__ float llvm_amdgcn_raw_buffer_load_fp32(v4i_t srsrc, int voffset,
                                                  int soffset, int glc_slc)
    __asm("llvm.amdgcn.raw.buffer.load.f32");

__device__ __forceinline__ float rl63(float x) {
    return __int_as_float(__builtin_amdgcn_readlane(__float_as_int(x), 63));
}
#define RLF(X, L) __int_as_float(__builtin_amdgcn_readlane(__float_as_int(X), (L)))

// input already pre-scaled by KTANH: tanh = 1 - 2/(1 + 2^xs)
__device__ __forceinline__ float fast_tanh_pre(float xs) {
    float e = __builtin_amdgcn_exp2f(xs);
    float u = __builtin_amdgcn_rcpf(1.0f + e);
    return __builtin_fmaf(-2.0f, u, 1.0f);
}

__device__ __forceinline__ h8 mk8(i32x2 a, i32x2 b) {
    i32x4 t = {a.x, a.y, b.x, b.y};
    return __builtin_bit_cast(h8, t);
}

struct TileAcc { float a0, a1, a2, a3, sc; };

// ---------------------------------------------------------------------------
// 16-edge tile (unchanged math from the passing R9/R22 kernels): LDS tile
// [64 feat][16 edge] f16 (d @0, d^2 @2048); packed f16 writes; fragments
// via ds_read_b64_tr_b16; 4x mfma(A, ones); lane-parallel LN; readlane
// rsig folds. Dep-carrying waitcnt (rule-18-safe) orders MFMA after the
// LDS reads without a sched_barrier.
// ---------------------------------------------------------------------------
#define TRRD(D, OFF)                                                           \
    asm volatile("ds_read_b64_tr_b16 %0, %1 offset:" OFF                       \
                 : "=v"(D) : "v"(trv))

template <bool GUARD>
__device__ __forceinline__ void tile16(
        TileAcc& A, float hn, int nrem,
        float h0, float h1, float h2, float h3,
        float h4, float h5, float h6, float h7,
        float h8v, float h9, float h10, float h11,
        float h12, float h13, float h14, float h15,
        char* wp, int trv, h8 ones) {
    float d0 = fast_tanh_pre(hn - h0);
    float d1 = fast_tanh_pre(hn - h1);
    float d2 = fast_tanh_pre(hn - h2);
    float d3 = fast_tanh_pre(hn - h3);
    float d4 = fast_tanh_pre(hn - h4);
    float d5 = fast_tanh_pre(hn - h5);
    float d6 = fast_tanh_pre(hn - h6);
    float d7 = fast_tanh_pre(hn - h7);
    float d8 = fast_tanh_pre(hn - h8v);
    float d9 = fast_tanh_pre(hn - h9);
    float d10 = fast_tanh_pre(hn - h10);
    float d11 = fast_tanh_pre(hn - h11);
    float d12 = fast_tanh_pre(hn - h12);
    float d13 = fast_tanh_pre(hn - h13);
    float d14 = fast_tanh_pre(hn - h14);
    float d15 = fast_tanh_pre(hn - h15);
    if (GUARD) {
        // invalid edges contribute exactly 0 (d=0 -> S1=S2=0 -> mu=0);
        // also kills junk from garbage-slot gathers.
        if (!(0 < nrem))  d0 = 0.f;
        if (!(1 < nrem))  d1 = 0.f;
        if (!(2 < nrem))  d2 = 0.f;
        if (!(3 < nrem))  d3 = 0.f;
        if (!(4 < nrem))  d4 = 0.f;
        if (!(5 < nrem))  d5 = 0.f;
        if (!(6 < nrem))  d6 = 0.f;
        if (!(7 < nrem))  d7 = 0.f;
        if (!(8 < nrem))  d8 = 0.f;
        if (!(9 < nrem))  d9 = 0.f;
        if (!(10 < nrem)) d10 = 0.f;
        if (!(11 < nrem)) d11 = 0.f;
        if (!(12 < nrem)) d12 = 0.f;
        if (!(13 < nrem)) d13 = 0.f;
        if (!(14 < nrem)) d14 = 0.f;
        if (!(15 < nrem)) d15 = 0.f;
    }
    hv2 p0 = __builtin_amdgcn_cvt_pkrtz(d0, d1);
    hv2 p1 = __builtin_amdgcn_cvt_pkrtz(d2, d3);
    hv2 p2 = __builtin_amdgcn_cvt_pkrtz(d4, d5);
    hv2 p3 = __builtin_amdgcn_cvt_pkrtz(d6, d7);
    hv2 p4 = __builtin_amdgcn_cvt_pkrtz(d8, d9);
    hv2 p5 = __builtin_amdgcn_cvt_pkrtz(d10, d11);
    hv2 p6 = __builtin_amdgcn_cvt_pkrtz(d12, d13);
    hv2 p7 = __builtin_amdgcn_cvt_pkrtz(d14, d15);
    hv2 q0 = p0 * p0, q1 = p1 * p1, q2 = p2 * p2, q3 = p3 * p3;
    hv2 q4 = p4 * p4, q5 = p5 * p5, q6 = p6 * p6, q7 = p7 * p7;
#define BC(X) __builtin_bit_cast(int, X)
    i32x4 wA = {BC(p0), BC(p1), BC(p2), BC(p3)};
    i32x4 wB = {BC(p4), BC(p5), BC(p6), BC(p7)};
    i32x4 wC = {BC(q0), BC(q1), BC(q2), BC(q3)};
    i32x4 wD = {BC(q4), BC(q5), BC(q6), BC(q7)};
#undef BC
    *(i32x4*)(wp)        = wA;
    *(i32x4*)(wp + 16)   = wB;
    *(i32x4*)(wp + 2048) = wC;
    *(i32x4*)(wp + 2064) = wD;
    asm volatile("" ::: "memory");   // stores stay before the tr reads
    i32x2 r0, r1, r2, r3, r4, r5, r6, r7;
    TRRD(r0, "0");    TRRD(r1, "128");
    TRRD(r2, "1024"); TRRD(r3, "1152");
    TRRD(r4, "2048"); TRRD(r5, "2176");
    TRRD(r6, "3072"); TRRD(r7, "3200");
    asm volatile("s_waitcnt lgkmcnt(0)"
                 : "+v"(r0), "+v"(r1), "+v"(r2), "+v"(r3),
                   "+v"(r4), "+v"(r5), "+v"(r6), "+v"(r7) :: "memory");
    h8 a0 = mk8(r0, r1), a1 = mk8(r2, r3);
    h8 b0 = mk8(r4, r5), b1 = mk8(r6, r7);
    f32x4 s1 = {0.f, 0.f, 0.f, 0.f}, s2 = {0.f, 0.f, 0.f, 0.f};
    s1 = __builtin_amdgcn_mfma_f32_16x16x32_f16(a0, ones, s1, 0, 0, 0);
    s1 = __builtin_amdgcn_mfma_f32_16x16x32_f16(a1, ones, s1, 0, 0, 0);
    s2 = __builtin_amdgcn_mfma_f32_16x16x32_f16(b0, ones, s2, 0, 0, 0);
    s2 = __builtin_amdgcn_mfma_f32_16x16x32_f16(b1, ones, s2, 0, 0, 0);
    float mu0 = s1[0] * 0.015625f;
    float mu1 = s1[1] * 0.015625f;
    float mu2 = s1[2] * 0.015625f;
    float mu3 = s1[3] * 0.015625f;
    float v0 = __builtin_fmaf(s2[0], 0.015625f, __builtin_fmaf(-mu0, mu0, LN_EPS));
    float v1 = __builtin_fmaf(s2[1], 0.015625f, __builtin_fmaf(-mu1, mu1, LN_EPS));
    float v2 = __builtin_fmaf(s2[2], 0.015625f, __builtin_fmaf(-mu2, mu2, LN_EPS));
    float v3 = __builtin_fmaf(s2[3], 0.015625f, __builtin_fmaf(-mu3, mu3, LN_EPS));
    float rs0 = __frsqrt_rn(v0);
    float rs1 = __frsqrt_rn(v1);
    float rs2 = __frsqrt_rn(v2);
    float rs3 = __frsqrt_rn(v3);
    A.sc += __builtin_fmaf(rs0, mu0,
            __builtin_fmaf(rs1, mu1,
            __builtin_fmaf(rs2, mu2, rs3 * mu3)));
    A.a0 = __builtin_fmaf(RLF(rs0, 0), d0, A.a0);
    A.a1 = __builtin_fmaf(RLF(rs1, 0), d1, A.a1);
    A.a2 = __builtin_fmaf(RLF(rs2, 0), d2, A.a2);
    A.a3 = __builtin_fmaf(RLF(rs3, 0), d3, A.a3);
    A.a0 = __builtin_fmaf(RLF(rs0, 16), d4, A.a0);
    A.a1 = __builtin_fmaf(RLF(rs1, 16), d5, A.a1);
    A.a2 = __builtin_fmaf(RLF(rs2, 16), d6, A.a2);
    A.a3 = __builtin_fmaf(RLF(rs3, 16), d7, A.a3);
    A.a0 = __builtin_fmaf(RLF(rs0, 32), d8, A.a0);
    A.a1 = __builtin_fmaf(RLF(rs1, 32), d9, A.a1);
    A.a2 = __builtin_fmaf(RLF(rs2, 32), d10, A.a2);
    A.a3 = __builtin_fmaf(RLF(rs3, 32), d11, A.a3);
    A.a0 = __builtin_fmaf(RLF(rs0, 48), d12, A.a0);
    A.a1 = __builtin_fmaf(RLF(rs1, 48), d13, A.a1);
    A.a2 = __builtin_fmaf(RLF(rs2, 48), d14, A.a2);
    A.a3 = __builtin_fmaf(RLF(rs3, 48), d15, A.a3);
}

// ---------------------------------------------------------------------------
// XCD-local scatter build (R23): each node has 8 sub-segments of CAPS=36
// ushort slots, one per XCD. A block appends only to its physical XCD's
// sub-segment (s_getreg HW_REG_XCC_ID, HW-verified m09) -> each XCD's dirty
// footprint = 50k x 72B ~ 3.6MB < its 4MiB L2 -> writes coalesce in L2
// instead of 2.9M random HBM line events (R10/R11 lesson). Edge-paired:
// EE threads handle both incidences. sub packs {hi16: #col, lo16: count}.
// ---------------------------------------------------------------------------
__global__ __launch_bounds__(256) void csr_build(const int* __restrict__ ei,
                                                 int* __restrict__ sub,
                                                 unsigned short* __restrict__ subadj) {
    int j = blockIdx.x * 256 + threadIdx.x;
    if (j >= EE) return;
    int u = ei[j];           // row node
    int v = ei[j + EE];      // col node
    int xcd;
    asm("s_getreg_b32 %0, hwreg(HW_REG_XCC_ID)" : "=s"(xcd));
    int r0 = atomicAdd(&sub[u * 8 + xcd], 1) & 0xffff;          // u: row role
    if (r0 < CAPS) subadj[(size_t)u * SUBW + xcd * CAPS + r0] = (unsigned short)v;
    int r1 = atomicAdd(&sub[v * 8 + xcd], 0x10001) & 0xffff;    // v: col role
    if (r1 < CAPS) subadj[(size_t)v * SUBW + xcd * CAPS + r1] = (unsigned short)u;
}

// ---------------------------------------------------------------------------
// Compaction (R23): one wave per node. Sequential 576B read of the 8
// sub-segments -> sequential 256B write of the compact CAP=128 segment +
// packed cnt. Prefix over 8 sub-degrees via lane0->LDS broadcast.
// ---------------------------------------------------------------------------
__global__ __launch_bounds__(256) void csr_compact(
        const int* __restrict__ sub, const unsigned short* __restrict__ subadj,
        int* __restrict__ cnt, unsigned short* __restrict__ adj) {
    __shared__ int pd[4][8];
    const int lane = threadIdx.x & 63, wv = threadIdx.x >> 6;
    for (int n = blockIdx.x * 4 + wv; n < NN; n += gridDim.x * 4) {
        const int* p = sub + n * 8;   // wave-uniform -> scalar loads
        int c0 = p[0], c1 = p[1], c2 = p[2], c3 = p[3];
        int c4 = p[4], c5 = p[5], c6 = p[6], c7 = p[7];
        if (lane == 0) {
            int pr = 0, dd;
#define STEP(S, C)                                                             \
            dd = (C) & 0xffff; if (dd > CAPS) dd = CAPS;                       \
            pd[wv][S] = (pr << 16) | dd; pr += dd;
            STEP(0, c0) STEP(1, c1) STEP(2, c2) STEP(3, c3)
            STEP(4, c4) STEP(5, c5) STEP(6, c6) STEP(7, c7)
#undef STEP
            int degraw = (c0 & 0xffff) + (c1 & 0xffff) + (c2 & 0xffff) +
                         (c3 & 0xffff) + (c4 & 0xffff) + (c5 & 0xffff) +
                         (c6 & 0xffff) + (c7 & 0xffff);
            int ncol = ((unsigned)c0 >> 16) + ((unsigned)c1 >> 16) +
                       ((unsigned)c2 >> 16) + ((unsigned)c3 >> 16) +
                       ((unsigned)c4 >> 16) + ((unsigned)c5 >> 16) +
                       ((unsigned)c6 >> 16) + ((unsigned)c7 >> 16);
            cnt[n] = (ncol << 16) | degraw;
        }
        // wave-level LDS write->read; compiler inserts the lgkmcnt wait
        const int s = lane >> 3;            // 8 lanes per sub-segment
        const int pdv = pd[wv][s];
        const int pre = pdv >> 16, ds = pdv & 0xffff;
        const unsigned short* src = subadj + (size_t)n * SUBW + s * CAPS;
        unsigned short* dst = adj + (size_t)n * CAP + pre;
        const int kb = lane & 7;
#pragma unroll
        for (int t = 0; t < 5; ++t) {
            int k = kb + 8 * t;
            if (k < CAPS && k < ds && pre + k < CAP) dst[k] = src[k];
        }
    }
}

// ---------------------------------------------------------------------------
// G = W @ W^T  (64x64). 16 blocks.
// ---------------------------------------------------------------------------
__global__ __launch_bounds__(256) void make_G(const float* __restrict__ W,
                                              float* __restrict__ G) {
    __shared__ float Ws[64 * 64];
    for (int t = threadIdx.x; t < 64 * 64; t += 256) Ws[t] = W[t];
    __syncthreads();
    int t = blockIdx.x * 256 + threadIdx.x;
    int i = t >> 6, j = t & 63;
    float acc = 0.f;
#pragma unroll 8
    for (int k = 0; k < 64; ++k) acc += Ws[i * 64 + k] * Ws[j * 64 + k];
    G[t] = acc;
}

// ---------------------------------------------------------------------------
// extractor: xh = x@We^T + be ; h0 = KTANH*(xh@U^T + bU) ; xU = (xh@U^T+bU)/nf
// ---------------------------------------------------------------------------
__global__ __launch_bounds__(256) void extractor(
        const float* __restrict__ x, const float* __restrict__ nf,
        const float* __restrict__ We, const float* __restrict__ be,
        const float* __restrict__ U,  const float* __restrict__ bU,
        float* __restrict__ xh, float* __restrict__ xU, float* __restrict__ h0) {
    __shared__ float WeT[INC * HH];
    __shared__ float UT[HH * HH];
    __shared__ float beS[HH], bUS[HH];
    __shared__ float xs[4][INC];
    __shared__ float xhs[4][HH];

    for (int t = threadIdx.x; t < INC * HH; t += 256) {
        int j = t >> 7, k = t & 127;
        WeT[k * 64 + j] = We[t];
    }
    for (int t = threadIdx.x; t < HH * HH; t += 256) {
        int j = t >> 6, k = t & 63;
        UT[k * 64 + j] = U[t];
    }
    if (threadIdx.x < 64) { beS[threadIdx.x] = be[threadIdx.x]; bUS[threadIdx.x] = bU[threadIdx.x]; }
    __syncthreads();

    int lane = threadIdx.x & 63;
    int wv   = threadIdx.x >> 6;

    for (int n0 = blockIdx.x * 4; n0 < NN; n0 += gridDim.x * 4) {
        int n = n0 + wv;
        bool valid = n < NN;
        if (valid) {
            xs[wv][lane]      = x[(size_t)n * INC + lane];
            xs[wv][lane + 64] = x[(size_t)n * INC + lane + 64];
        }
        __syncthreads();
        float acc = beS[lane];
        if (valid) {
#pragma unroll 8
            for (int k = 0; k < INC; ++k) acc += xs[wv][k] * WeT[k * 64 + lane];
            xh[n * 64 + lane] = acc;
            xhs[wv][lane] = acc;
        }
        __syncthreads();
        if (valid) {
            float acc2 = bUS[lane];
#pragma unroll 8
            for (int k = 0; k < HH; ++k) acc2 += xhs[wv][k] * UT[k * 64 + lane];
            h0[n * 64 + lane] = KTANH * acc2;
            xU[n * 64 + lane] = acc2 / nf[n];
        }
        __syncthreads();
    }
}

// ---------------------------------------------------------------------------
// fused step v16 (R22, unchanged): packed ushort adj -- ONE 64-lane int load
// covers all 128 entries of a node; no chunk loop. Entry j lives in lane
// j>>1, half j&1. Junk-slot gathers are bounded (<=65535*256; OOB -> 0) and
// guarded tiles zero junk d. Depth-8 tile tree with one-tile-ahead prefetch.
// ---------------------------------------------------------------------------
#define HV(P) P##0, P##1, P##2, P##3, P##4, P##5, P##6, P##7,                 \
              P##8, P##9, P##10, P##11, P##12, P##13, P##14, P##15

#define EVX(EV, J)                                                             \
    ((((RL((EV), (J) >> 1)) >> (((J) & 1) << 4)) & 0xffff) << 8)

#define G16P(P, EV, J)                                                         \
    do {                                                                       \
        P##0  = GATH(EVX(EV, (J) + 0));  P##1  = GATH(EVX(EV, (J) + 1));       \
        P##2  = GATH(EVX(EV, (J) + 2));  P##3  = GATH(EVX(EV, (J) + 3));       \
        P##4  = GATH(EVX(EV, (J) + 4));  P##5  = GATH(EVX(EV, (J) + 5));       \
        P##6  = GATH(EVX(EV, (J) + 6));  P##7  = GATH(EVX(EV, (J) + 7));       \
        P##8  = GATH(EVX(EV, (J) + 8));  P##9  = GATH(EVX(EV, (J) + 9));       \
        P##10 = GATH(EVX(EV, (J) + 10)); P##11 = GATH(EVX(EV, (J) + 11));      \
        P##12 = GATH(EVX(EV, (J) + 12)); P##13 = GATH(EVX(EV, (J) + 13));      \
        P##14 = GATH(EVX(EV, (J) + 14)); P##15 = GATH(EVX(EV, (J) + 15));      \
    } while (0)

#define NPREF(P)                                                               \
    do { if (morenode) { G16P(P, evN, 0); } } while (0)

#define TILF(BUF) tile16<false>(A, hn, 16, HV(BUF), wp, trv, ones)
#define TILG(BUF, NR) tile16<true>(A, hn, (NR), HV(BUF), wp, trv, ones)

__global__ __launch_bounds__(256) void fused_step(
        const int* __restrict__ adjI,
        const int* __restrict__ cnt,
        const float* __restrict__ hcur, float* __restrict__ hnxt,
        const float* __restrict__ nf, const float* __restrict__ gamma,
        const float* __restrict__ beta, const float* __restrict__ Gm,
        const float* __restrict__ xU,
        float* __restrict__ y, float* __restrict__ s, int first, int last) {
    __shared__ float Gs[64 * 64];
    __shared__ __align__(16) _Float16 dt[4][2048];
    for (int t = threadIdx.x; t < 64 * 64; t += 256) Gs[t] = Gm[t];
    __syncthreads();

    const int lane = threadIdx.x & 63, wv = threadIdx.x >> 6;
    const float g = gamma[lane], b = beta[lane];

    v4i_t hsr;
    {
        unsigned long long up = (unsigned long long)(uintptr_t)hcur;
        hsr.x = (int)(unsigned)(up & 0xffffffffull);
        hsr.y = (int)(unsigned)(up >> 32);
        hsr.z = NN * HH * 4;
        hsr.w = 0x00020000;
    }
    const int lane4 = lane << 2;
#define GATH(e) llvm_amdgcn_raw_buffer_load_fp32(hsr, lane4, (e), 0)
#define RL(v, i) __builtin_amdgcn_readlane((v), (i))

    _Float16* tb = &dt[wv][0];
    char* wp = (char*)tb + lane * 32;                       // write row base
    const unsigned tbb = (unsigned)(uintptr_t)tb;           // LDS byte offset
    const int trv = (int)(tbb + ((lane >> 4) << 8) + ((lane & 15) << 3));
    const h8 ones = {(_Float16)1.f, (_Float16)1.f, (_Float16)1.f, (_Float16)1.f,
                     (_Float16)1.f, (_Float16)1.f, (_Float16)1.f, (_Float16)1.f};

    const int NW = 2048 * 4;
    int n = blockIdx.x * 4 + wv;       // NW < NN so always valid
    int cP   = __builtin_amdgcn_readfirstlane(cnt[n]);
    int deg  = cP & 0xffff;  if (deg > CAP) deg = CAP;
    int sgm  = (cP & 0xffff) - 2 * ((int)((unsigned)cP >> 16));
    int evl  = adjI[n * (CAP / 2) + lane];   // 64 ints = 128 packed entries
    float hn = hcur[(size_t)n * 64 + lane];
    float hA0, hA1, hA2, hA3, hA4, hA5, hA6, hA7;
    float hA8, hA9, hA10, hA11, hA12, hA13, hA14, hA15;
    float hB0, hB1, hB2, hB3, hB4, hB5, hB6, hB7;
    float hB8, hB9, hB10, hB11, hB12, hB13, hB14, hB15;
    G16P(hA, evl, 0);

    for (;;) {
        const int nxt = n + NW;
        const bool morenode = nxt < NN;
        int cN = 0, evN = 0;
        float hnN = 0.f;
        if (morenode) {
            cN  = __builtin_amdgcn_readfirstlane(cnt[nxt]);
            evN = adjI[nxt * (CAP / 2) + lane];
            hnN = hcur[(size_t)nxt * 64 + lane];
        }
        TileAcc A = {0.f, 0.f, 0.f, 0.f, 0.f};

        if (deg > 0) {
            const int nt = (deg + 15) >> 4;   // 1..8
            if (nt > 1) { G16P(hB, evl, 16); } else { NPREF(hB); }
            if (nt == 1) { TILG(hA, deg); }
            else {
                TILF(hA);                                      // tile 0
                if (nt > 2) { G16P(hA, evl, 32); } else { NPREF(hA); }
                if (nt == 2) { TILG(hB, deg - 16); }
                else {
                    TILF(hB);                                  // tile 1
                    if (nt > 3) { G16P(hB, evl, 48); } else { NPREF(hB); }
                    if (nt == 3) { TILG(hA, deg - 32); }
                    else {
                        TILF(hA);                              // tile 2
                        if (nt > 4) { G16P(hA, evl, 64); } else { NPREF(hA); }
                        if (nt == 4) { TILG(hB, deg - 48); }
                        else {
                            TILF(hB);                          // tile 3
                            if (nt > 5) { G16P(hB, evl, 80); } else { NPREF(hB); }
                            if (nt == 5) { TILG(hA, deg - 64); }
                            else {
                                TILF(hA);                      // tile 4
                                if (nt > 6) { G16P(hA, evl, 96); } else { NPREF(hA); }
                                if (nt == 6) { TILG(hB, deg - 80); }
                                else {
                                    TILF(hB);                  // tile 5
                                    if (nt > 7) { G16P(hB, evl, 112); } else { NPREF(hB); }
                                    if (nt == 7) { TILG(hA, deg - 96); }
                                    else {
                                        TILF(hA);              // tile 6
                                        NPREF(hA);
                                        TILG(hB, deg - 112);   // tile 7
                                    }
                                }
                            }
                        }
                    }
                }
            }
            if (nt & 1) {   // odd nt: next-node prefetch landed in hB
                hA0 = hB0;  hA1 = hB1;  hA2 = hB2;  hA3 = hB3;
                hA4 = hB4;  hA5 = hB5;  hA6 = hB6;  hA7 = hB7;
                hA8 = hB8;  hA9 = hB9;  hA10 = hB10; hA11 = hB11;
                hA12 = hB12; hA13 = hB13; hA14 = hB14; hA15 = hB15;
            }
        } else {
            NPREF(hA);
        }

        // ---- epilogue: combine per-lane cs partials (row-uniform) once
        float scp = A.sc;
        asm volatile(
            "s_nop 1\n\t"
            "v_add_f32_dpp %0, %0, %0 row_bcast:15 row_mask:0xa bank_mask:0xf bound_ctrl:0\n\t"
            "s_nop 1\n\t"
            "v_add_f32_dpp %0, %0, %0 row_bcast:31 row_mask:0xc bank_mask:0xf bound_ctrl:0"
            : "+v"(scp));
        const float accM = ((A.a0 + A.a1) + (A.a2 + A.a3)) - rl63(scp);
        const float nfn = nf[n];
        const float av  = nfn * __builtin_fmaf(g, accM, b * (float)sgm);

        float p = 0.f;
        const int avi = __float_as_int(av);
#pragma unroll
        for (int k = 0; k < 64; ++k) {
            float ak = __int_as_float(RL(avi, k));
            p = __builtin_fmaf(ak, Gs[k * 64 + lane], p);
        }

        float yprev = 0.f, sprev = 0.f;
        if (!first) {
            yprev = y[n * 64 + lane];
            sprev = s[n * 64 + lane];
        }
        const float yv = -ALPHA * p + (1.0f - ALPHA) * yprev;
        y[n * 64 + lane] = yv;
        s[n * 64 + lane] = (1.0f - ALPHA) * sprev + av;
        if (!last) hnxt[n * 64 + lane] = KTANH * (nfn * (yv + xU[n * 64 + lane]));

        if (!morenode) break;
        n = nxt;
        deg = cN & 0xffff;  if (deg > CAP) deg = CAP;
        sgm = (cN & 0xffff) - 2 * ((int)((unsigned)cN >> 16));
        evl = evN; hn = hnN;
    }
#undef GATH
#undef RL
}

// ---------------------------------------------------------------------------
// final: z = -alpha*(s@W) ; zf = nf*z + xh ; out = zf@Wlast^T + blast
// ---------------------------------------------------------------------------
__global__ __launch_bounds__(256) void final_out(
        const float* __restrict__ s, const float* __restrict__ xh,
        const float* __restrict__ nf, const float* __restrict__ W,
        const float* __restrict__ Wlast, const float* __restrict__ blast,
        float* __restrict__ out) {
    __shared__ float Ws[64 * 64];
    __shared__ float WlT[64 * OUTC];
    __shared__ float blS[OUTC];
    __shared__ float ss[4][64];
    __shared__ float zfs[4][64];
    for (int t = threadIdx.x; t < 64 * 64; t += 256) Ws[t] = W[t];
    for (int t = threadIdx.x; t < OUTC * 64; t += 256) {
        int o = t >> 6, j = t & 63;
        WlT[j * OUTC + o] = Wlast[t];
    }
    if (threadIdx.x < OUTC) blS[threadIdx.x] = blast[threadIdx.x];
    __syncthreads();
    int lane = threadIdx.x & 63, wv = threadIdx.x >> 6;
    for (int n0 = blockIdx.x * 4; n0 < NN; n0 += gridDim.x * 4) {
        int n = n0 + wv;
        if (n < NN) ss[wv][lane] = s[n * 64 + lane];
        __syncthreads();
        if (n < NN) {
            float z = 0.f;
#pragma unroll 8
            for (int k = 0; k < 64; ++k) z += ss[wv][k] * Ws[k * 64 + lane];
            z *= -ALPHA;
            zfs[wv][lane] = nf[n] * z + xh[n * 64 + lane];
        }
        __syncthreads();
        if (n < NN && lane < OUTC) {
            float acc = blS[lane];
#pragma unroll 8
            for (int j = 0; j < 64; ++j) acc += zfs[wv][j] * WlT[j * OUTC + lane];
            out[n * OUTC + lane] = acc;
        }
        __syncthreads();
    }
}

// ---------------------------------------------------------------------------
extern "C" void kernel_launch(void* const* d_in, const int* in_sizes, int n_in,
                              void* d_out, int out_size, void* d_ws, size_t ws_size,
                              hipStream_t stream) {
    const float* x     = (const float*)d_in[0];
    const int*   ei    = (const int*)  d_in[1];
    const float* nf    = (const float*)d_in[2];
    const float* We    = (const float*)d_in[3];
    const float* be    = (const float*)d_in[4];
    const float* W     = (const float*)d_in[5];
    const float* U     = (const float*)d_in[6];
    const float* bU    = (const float*)d_in[7];
    const float* gamma = (const float*)d_in[8];
    const float* beta  = (const float*)d_in[9];
    const float* Wlast = (const float*)d_in[10];
    const float* blast = (const float*)d_in[11];
    float* out = (float*)d_out;

    char* ws = (char*)d_ws;
    size_t off = 0;
    const size_t NH = (size_t)NN * HH * sizeof(float);
    unsigned short* adj = (unsigned short*)(ws + off);
                                                 off += (size_t)NN * CAP * sizeof(unsigned short) + 256;
    unsigned short* subadj = (unsigned short*)(ws + off);
                                                 off += (size_t)NN * SUBW * sizeof(unsigned short) + 256;
    int*   sub    = (int*)(ws + off);            off += (size_t)NN * 8 * sizeof(int);
    int*   cnt    = (int*)(ws + off);            off += (size_t)NN * sizeof(int);
    float* xh     = (float*)(ws + off);          off += NH;
    float* xU     = (float*)(ws + off);          off += NH;
    float* h0     = (float*)(ws + off);          off += NH;
    float* h1     = (float*)(ws + off);          off += NH;
    float* y      = (float*)(ws + off);          off += NH;
    float* s      = (float*)(ws + off);          off += NH;
    float* G      = (float*)(ws + off);          off += (size_t)HH * HH * sizeof(float);

    (void)hipMemsetAsync(sub, 0, (size_t)NN * 8 * sizeof(int), stream);
    // y/s zero-init folded into fused_step (first=1)

    csr_build<<<(EE + 255) / 256, 256, 0, stream>>>(ei, sub, subadj);
    csr_compact<<<2048, 256, 0, stream>>>(sub, subadj, cnt, adj);

    make_G<<<16, 256, 0, stream>>>(W, G);
    extractor<<<2048, 256, 0, stream>>>(x, nf, We, be, U, bU, xh, xU, h0);

    float* hc = h0;
    float* hn = h1;
    for (int t = 0; t < 4; ++t) {
        fused_step<<<2048, 256, 0, stream>>>((const int*)adj, cnt, hc, hn, nf,
                                             gamma, beta, G, xU, y, s,
                                             t == 0, t == 3);
        float* tmp = hc; hc = hn; hn = tmp;
    }
    final_out<<<2048, 256, 0, stream>>>(s, xh, nf, W, Wlast, blast, out);
}

// Round 13
// 962.596 us; speedup vs baseline: 1.1416x; 1.1416x over previous
//
#include <hip/hip_runtime.h>
#include <hip/hip_bf16.h>

// Problem constants (from reference)
#define NN   50000
#define EE   1600000
#define INC  128
#define HH   64
#define OUTC 40
#define ALPHA 0.8f
#define LN_EPS 1e-5f
#define NB_SCAN 196   // ceil(NN/256)
// h is stored pre-scaled by 2*log2(e) so tanh needs no per-edge multiply:
// tanh(x) = 1 - 2/(1 + 2^(KTANH*x)).  (R8 lesson: polynomial tanh approx
// is NOT safe here -- LN divides by sigma which can be ~sqrt(eps), so
// absolute tanh error amplifies ~300x. Keep the exact exp2 form.)
#define KTANH 2.8853900817779268f

typedef int v4i_t __attribute__((ext_vector_type(4)));
typedef _Float16 h8 __attribute__((ext_vector_type(8)));
typedef __fp16 hv2 __attribute__((ext_vector_type(2)));   // cvt_pkrtz's type
typedef float f32x4 __attribute__((ext_vector_type(4)));
typedef int i32x2 __attribute__((ext_vector_type(2)));
typedef int i32x4 __attribute__((ext_vector_type(4)));

__device__ float llvm_amdgcn_raw_buffer_load_fp32(v4i_t srsrc, int voffset,
                                                  int soffset, int glc_slc)
    __asm("llvm.amdgcn.raw.buffer.load.f32");

__device__ __forceinline__ float rl63(float x) {
    return __int_as_float(__builtin_amdgcn_readlane(__float_as_int(x), 63));
}
#define RLF(X, L) __int_as_float(__builtin_amdgcn_readlane(__float_as_int(X), (L)))

// input already pre-scaled by KTANH: tanh = 1 - 2/(1 + 2^xs)
__device__ __forceinline__ float fast_tanh_pre(float xs) {
    float e = __builtin_amdgcn_exp2f(xs);
    float u = __builtin_amdgcn_rcpf(1.0f + e);
    return __builtin_fmaf(-2.0f, u, 1.0f);
}

__device__ __forceinline__ h8 mk8(i32x2 a, i32x2 b) {
    i32x4 t = {a.x, a.y, b.x, b.y};
    return __builtin_bit_cast(h8, t);
}

struct TileAcc { float a0, a1, a2, a3, sc; };

// ---------------------------------------------------------------------------
// 16-edge tile (identical math to the passing R9 kernel): LDS tile
// [64 feat][16 edge] f16 (d @0, d^2 @2048); packed f16 writes; fragments
// via ds_read_b64_tr_b16; 4x mfma(A, ones); lane-parallel LN; readlane
// rsig folds. Dep-carrying waitcnt (rule-18-safe) orders MFMA after the
// LDS reads without a sched_barrier.
// ---------------------------------------------------------------------------
#define TRRD(D, OFF)                                                           \
    asm volatile("ds_read_b64_tr_b16 %0, %1 offset:" OFF                       \
                 : "=v"(D) : "v"(trv))

template <bool GUARD>
__device__ __forceinline__ void tile16(
        TileAcc& A, float hn, int nrem,
        float h0, float h1, float h2, float h3,
        float h4, float h5, float h6, float h7,
        float h8v, float h9, float h10, float h11,
        float h12, float h13, float h14, float h15,
        char* wp, int trv, h8 ones) {
    float d0 = fast_tanh_pre(hn - h0);
    float d1 = fast_tanh_pre(hn - h1);
    float d2 = fast_tanh_pre(hn - h2);
    float d3 = fast_tanh_pre(hn - h3);
    float d4 = fast_tanh_pre(hn - h4);
    float d5 = fast_tanh_pre(hn - h5);
    float d6 = fast_tanh_pre(hn - h6);
    float d7 = fast_tanh_pre(hn - h7);
    float d8 = fast_tanh_pre(hn - h8v);
    float d9 = fast_tanh_pre(hn - h9);
    float d10 = fast_tanh_pre(hn - h10);
    float d11 = fast_tanh_pre(hn - h11);
    float d12 = fast_tanh_pre(hn - h12);
    float d13 = fast_tanh_pre(hn - h13);
    float d14 = fast_tanh_pre(hn - h14);
    float d15 = fast_tanh_pre(hn - h15);
    if (GUARD) {
        // invalid edges contribute exactly 0 (d=0 -> S1=S2=0 -> mu=0);
        // also kills junk from garbage-slot gathers.
        if (!(0 < nrem))  d0 = 0.f;
        if (!(1 < nrem))  d1 = 0.f;
        if (!(2 < nrem))  d2 = 0.f;
        if (!(3 < nrem))  d3 = 0.f;
        if (!(4 < nrem))  d4 = 0.f;
        if (!(5 < nrem))  d5 = 0.f;
        if (!(6 < nrem))  d6 = 0.f;
        if (!(7 < nrem))  d7 = 0.f;
        if (!(8 < nrem))  d8 = 0.f;
        if (!(9 < nrem))  d9 = 0.f;
        if (!(10 < nrem)) d10 = 0.f;
        if (!(11 < nrem)) d11 = 0.f;
        if (!(12 < nrem)) d12 = 0.f;
        if (!(13 < nrem)) d13 = 0.f;
        if (!(14 < nrem)) d14 = 0.f;
        if (!(15 < nrem)) d15 = 0.f;
    }
    hv2 p0 = __builtin_amdgcn_cvt_pkrtz(d0, d1);
    hv2 p1 = __builtin_amdgcn_cvt_pkrtz(d2, d3);
    hv2 p2 = __builtin_amdgcn_cvt_pkrtz(d4, d5);
    hv2 p3 = __builtin_amdgcn_cvt_pkrtz(d6, d7);
    hv2 p4 = __builtin_amdgcn_cvt_pkrtz(d8, d9);
    hv2 p5 = __builtin_amdgcn_cvt_pkrtz(d10, d11);
    hv2 p6 = __builtin_amdgcn_cvt_pkrtz(d12, d13);
    hv2 p7 = __builtin_amdgcn_cvt_pkrtz(d14, d15);
    hv2 q0 = p0 * p0, q1 = p1 * p1, q2 = p2 * p2, q3 = p3 * p3;
    hv2 q4 = p4 * p4, q5 = p5 * p5, q6 = p6 * p6, q7 = p7 * p7;
#define BC(X) __builtin_bit_cast(int, X)
    i32x4 wA = {BC(p0), BC(p1), BC(p2), BC(p3)};
    i32x4 wB = {BC(p4), BC(p5), BC(p6), BC(p7)};
    i32x4 wC = {BC(q0), BC(q1), BC(q2), BC(q3)};
    i32x4 wD = {BC(q4), BC(q5), BC(q6), BC(q7)};
#undef BC
    *(i32x4*)(wp)        = wA;
    *(i32x4*)(wp + 16)   = wB;
    *(i32x4*)(wp + 2048) = wC;
    *(i32x4*)(wp + 2064) = wD;
    asm volatile("" ::: "memory");   // stores stay before the tr reads
    i32x2 r0, r1, r2, r3, r4, r5, r6, r7;
    TRRD(r0, "0");    TRRD(r1, "128");
    TRRD(r2, "1024"); TRRD(r3, "1152");
    TRRD(r4, "2048"); TRRD(r5, "2176");
    TRRD(r6, "3072"); TRRD(r7, "3200");
    asm volatile("s_waitcnt lgkmcnt(0)"
                 : "+v"(r0), "+v"(r1), "+v"(r2), "+v"(r3),
                   "+v"(r4), "+v"(r5), "+v"(r6), "+v"(r7) :: "memory");
    h8 a0 = mk8(r0, r1), a1 = mk8(r2, r3);
    h8 b0 = mk8(r4, r5), b1 = mk8(r6, r7);
    f32x4 s1 = {0.f, 0.f, 0.f, 0.f}, s2 = {0.f, 0.f, 0.f, 0.f};
    s1 = __builtin_amdgcn_mfma_f32_16x16x32_f16(a0, ones, s1, 0, 0, 0);
    s1 = __builtin_amdgcn_mfma_f32_16x16x32_f16(a1, ones, s1, 0, 0, 0);
    s2 = __builtin_amdgcn_mfma_f32_16x16x32_f16(b0, ones, s2, 0, 0, 0);
    s2 = __builtin_amdgcn_mfma_f32_16x16x32_f16(b1, ones, s2, 0, 0, 0);
    float mu0 = s1[0] * 0.015625f;
    float mu1 = s1[1] * 0.015625f;
    float mu2 = s1[2] * 0.015625f;
    float mu3 = s1[3] * 0.015625f;
    float v0 = __builtin_fmaf(s2[0], 0.015625f, __builtin_fmaf(-mu0, mu0, LN_EPS));
    float v1 = __builtin_fmaf(s2[1], 0.015625f, __builtin_fmaf(-mu1, mu1, LN_EPS));
    float v2 = __builtin_fmaf(s2[2], 0.015625f, __builtin_fmaf(-mu2, mu2, LN_EPS));
    float v3 = __builtin_fmaf(s2[3], 0.015625f, __builtin_fmaf(-mu3, mu3, LN_EPS));
    float rs0 = __frsqrt_rn(v0);
    float rs1 = __frsqrt_rn(v1);
    float rs2 = __frsqrt_rn(v2);
    float rs3 = __frsqrt_rn(v3);
    A.sc += __builtin_fmaf(rs0, mu0,
            __builtin_fmaf(rs1, mu1,
            __builtin_fmaf(rs2, mu2, rs3 * mu3)));
    A.a0 = __builtin_fmaf(RLF(rs0, 0), d0, A.a0);
    A.a1 = __builtin_fmaf(RLF(rs1, 0), d1, A.a1);
    A.a2 = __builtin_fmaf(RLF(rs2, 0), d2, A.a2);
    A.a3 = __builtin_fmaf(RLF(rs3, 0), d3, A.a3);
    A.a0 = __builtin_fmaf(RLF(rs0, 16), d4, A.a0);
    A.a1 = __builtin_fmaf(RLF(rs1, 16), d5, A.a1);
    A.a2 = __builtin_fmaf(RLF(rs2, 16), d6, A.a2);
    A.a3 = __builtin_fmaf(RLF(rs3, 16), d7, A.a3);
    A.a0 = __builtin_fmaf(RLF(rs0, 32), d8, A.a0);
    A.a1 = __builtin_fmaf(RLF(rs1, 32), d9, A.a1);
    A.a2 = __builtin_fmaf(RLF(rs2, 32), d10, A.a2);
    A.a3 = __builtin_fmaf(RLF(rs3, 32), d11, A.a3);
    A.a0 = __builtin_fmaf(RLF(rs0, 48), d12, A.a0);
    A.a1 = __builtin_fmaf(RLF(rs1, 48), d13, A.a1);
    A.a2 = __builtin_fmaf(RLF(rs2, 48), d14, A.a2);
    A.a3 = __builtin_fmaf(RLF(rs3, 48), d15, A.a3);
}

// ---------------------------------------------------------------------------
// CSR build (R9's split pipeline -- measured fastest of all build variants;
// R10-R12 single-pass/XCD-local variants all lost to scatter-write line
// amplification). cnt packs {hi16: #col-role, lo16: degree} via one
// atomicAdd; rank16 write is coalesced; fill is a pure scatter with no
// atomic dependency. adj entry = other*256 (raw h-row byte offset).
// ---------------------------------------------------------------------------
__global__ __launch_bounds__(256) void csr_count(const int* __restrict__ ei,
                                                 int* __restrict__ cnt,
                                                 unsigned short* __restrict__ rank16) {
    int i = blockIdx.x * 256 + threadIdx.x;
    if (i >= 2 * EE) return;
    int add = (i >= EE) ? 0x10001 : 1;
    int r = atomicAdd(&cnt[ei[i]], add);
    rank16[i] = (unsigned short)r;   // low16 of old value = rank
}

__global__ __launch_bounds__(256) void scanA(const int* __restrict__ cnt,
                                             int* __restrict__ offs,
                                             int* __restrict__ bsum) {
    __shared__ int tmp[256];
    int i = blockIdx.x * 256 + threadIdx.x;
    int v = (i < NN) ? (cnt[i] & 0xffff) : 0;
    tmp[threadIdx.x] = v;
    __syncthreads();
    int acc = v;
    for (int d = 1; d < 256; d <<= 1) {
        int t = (threadIdx.x >= d) ? tmp[threadIdx.x - d] : 0;
        __syncthreads();
        acc += t;
        tmp[threadIdx.x] = acc;
        __syncthreads();
    }
    if (i < NN) offs[i] = acc - v;
    if (threadIdx.x == 255) bsum[blockIdx.x] = acc;
}

__global__ __launch_bounds__(256) void scanB(int* __restrict__ bsum) {
    __shared__ int tmp[256];
    int v = (threadIdx.x < NB_SCAN) ? bsum[threadIdx.x] : 0;
    tmp[threadIdx.x] = v;
    __syncthreads();
    int acc = v;
    for (int d = 1; d < 256; d <<= 1) {
        int t = (threadIdx.x >= d) ? tmp[threadIdx.x - d] : 0;
        __syncthreads();
        acc += t;
        tmp[threadIdx.x] = acc;
        __syncthreads();
    }
    if (threadIdx.x < NB_SCAN) bsum[threadIdx.x] = acc - v;
}

__global__ __launch_bounds__(256) void scanC(int* __restrict__ offs,
                                             const int* __restrict__ bsum) {
    int i = blockIdx.x * 256 + threadIdx.x;
    if (i < NN) offs[i] += bsum[blockIdx.x];
}

__global__ __launch_bounds__(256) void csr_fill(const int* __restrict__ ei,
                                                const int* __restrict__ offs,
                                                const unsigned short* __restrict__ rank16,
                                                int* __restrict__ adj) {
    int i = blockIdx.x * 256 + threadIdx.x;
    if (i >= 2 * EE) return;
    int node  = ei[i];
    int other = (i >= EE) ? ei[i - EE] : ei[i + EE];
    adj[offs[node] + (int)rank16[i]] = other << 8;
}

// ---------------------------------------------------------------------------
// G = W @ W^T  (64x64), stored as f16 (R24: halves the fused_step Gs LDS
// -> 24KB/block -> 6 blocks/CU, +20% waves). |G|<~2, f16 rel err 5e-4
// -> output error << threshold headroom. 16 blocks.
// ---------------------------------------------------------------------------
__global__ __launch_bounds__(256) void make_G(const float* __restrict__ W,
                                              _Float16* __restrict__ G) {
    __shared__ float Ws[64 * 64];
    for (int t = threadIdx.x; t < 64 * 64; t += 256) Ws[t] = W[t];
    __syncthreads();
    int t = blockIdx.x * 256 + threadIdx.x;
    int i = t >> 6, j = t & 63;
    float acc = 0.f;
#pragma unroll 8
    for (int k = 0; k < 64; ++k) acc += Ws[i * 64 + k] * Ws[j * 64 + k];
    G[t] = (_Float16)acc;
}

// ---------------------------------------------------------------------------
// extractor: xh = x@We^T + be ; h0 = KTANH*(xh@U^T + bU) ; xU = (xh@U^T+bU)/nf
// ---------------------------------------------------------------------------
__global__ __launch_bounds__(256) void extractor(
        const float* __restrict__ x, const float* __restrict__ nf,
        const float* __restrict__ We, const float* __restrict__ be,
        const float* __restrict__ U,  const float* __restrict__ bU,
        float* __restrict__ xh, float* __restrict__ xU, float* __restrict__ h0) {
    __shared__ float WeT[INC * HH];
    __shared__ float UT[HH * HH];
    __shared__ float beS[HH], bUS[HH];
    __shared__ float xs[4][INC];
    __shared__ float xhs[4][HH];

    for (int t = threadIdx.x; t < INC * HH; t += 256) {
        int j = t >> 7, k = t & 127;
        WeT[k * 64 + j] = We[t];
    }
    for (int t = threadIdx.x; t < HH * HH; t += 256) {
        int j = t >> 6, k = t & 63;
        UT[k * 64 + j] = U[t];
    }
    if (threadIdx.x < 64) { beS[threadIdx.x] = be[threadIdx.x]; bUS[threadIdx.x] = bU[threadIdx.x]; }
    __syncthreads();

    int lane = threadIdx.x & 63;
    int wv   = threadIdx.x >> 6;

    for (int n0 = blockIdx.x * 4; n0 < NN; n0 += gridDim.x * 4) {
        int n = n0 + wv;
        bool valid = n < NN;
        if (valid) {
            xs[wv][lane]      = x[(size_t)n * INC + lane];
            xs[wv][lane + 64] = x[(size_t)n * INC + lane + 64];
        }
        __syncthreads();
        float acc = beS[lane];
        if (valid) {
#pragma unroll 8
            for (int k = 0; k < INC; ++k) acc += xs[wv][k] * WeT[k * 64 + lane];
            xh[n * 64 + lane] = acc;
            xhs[wv][lane] = acc;
        }
        __syncthreads();
        if (valid) {
            float acc2 = bUS[lane];
#pragma unroll 8
            for (int k = 0; k < HH; ++k) acc2 += xhs[wv][k] * UT[k * 64 + lane];
            h0[n * 64 + lane] = KTANH * acc2;
            xU[n * 64 + lane] = acc2 / nf[n];
        }
        __syncthreads();
    }
}

// ---------------------------------------------------------------------------
// fused step (R24 = R9's passing v14 + f16 Gs): exp2 tanh, dep-carrying
// waitcnt, tr-read LDS tiles, precomputed sigma. LDS 24KB -> 6 blocks/CU.
// ---------------------------------------------------------------------------
#define HV(P) P##0, P##1, P##2, P##3, P##4, P##5, P##6, P##7,                 \
              P##8, P##9, P##10, P##11, P##12, P##13, P##14, P##15

#define G16(P, EV, J)                                                          \
    do {                                                                       \
        P##0  = GATH(RL(EV, (J) + 0));  P##1  = GATH(RL(EV, (J) + 1));         \
        P##2  = GATH(RL(EV, (J) + 2));  P##3  = GATH(RL(EV, (J) + 3));         \
        P##4  = GATH(RL(EV, (J) + 4));  P##5  = GATH(RL(EV, (J) + 5));         \
        P##6  = GATH(RL(EV, (J) + 6));  P##7  = GATH(RL(EV, (J) + 7));         \
        P##8  = GATH(RL(EV, (J) + 8));  P##9  = GATH(RL(EV, (J) + 9));         \
        P##10 = GATH(RL(EV, (J) + 10)); P##11 = GATH(RL(EV, (J) + 11));        \
        P##12 = GATH(RL(EV, (J) + 12)); P##13 = GATH(RL(EV, (J) + 13));        \
        P##14 = GATH(RL(EV, (J) + 14)); P##15 = GATH(RL(EV, (J) + 15));        \
    } while (0)

#define NEXTPREF(P)                                                            \
    do {                                                                       \
        if (morechunk)      { G16(P, evB, 0); }                                \
        else if (morenode)  { G16(P, evN, 0); }                                \
    } while (0)

__global__ __launch_bounds__(256) void fused_step(
        const int* __restrict__ adj, const int* __restrict__ offs,
        const int* __restrict__ cnt,
        const float* __restrict__ hcur, float* __restrict__ hnxt,
        const float* __restrict__ nf, const float* __restrict__ gamma,
        const float* __restrict__ beta, const _Float16* __restrict__ Gm,
        const float* __restrict__ xU,
        float* __restrict__ y, float* __restrict__ s, int first, int last) {
    __shared__ _Float16 Gs[64 * 64];
    __shared__ __align__(16) _Float16 dt[4][2048];
    for (int t = threadIdx.x; t < 64 * 64; t += 256) Gs[t] = Gm[t];
    __syncthreads();

    const int lane = threadIdx.x & 63, wv = threadIdx.x >> 6;
    const float g = gamma[lane], b = beta[lane];

    v4i_t hsr;
    {
        unsigned long long up = (unsigned long long)(uintptr_t)hcur;
        hsr.x = (int)(unsigned)(up & 0xffffffffull);
        hsr.y = (int)(unsigned)(up >> 32);
        hsr.z = NN * HH * 4;
        hsr.w = 0x00020000;
    }
    const int lane4 = lane << 2;
#define GATH(e) llvm_amdgcn_raw_buffer_load_fp32(hsr, lane4, (e), 0)
#define RL(v, i) __builtin_amdgcn_readlane((v), (i))

    _Float16* tb = &dt[wv][0];
    char* wp = (char*)tb + lane * 32;                       // write row base
    const unsigned tbb = (unsigned)(uintptr_t)tb;           // LDS byte offset
    // TR base: group g=(l>>4) at feature-block 2g (g*256B); lane-in-group
    // i=(l&15) loads its own 8B chunk at i*8.
    const int trv = (int)(tbb + ((lane >> 4) << 8) + ((lane & 15) << 3));
    const h8 ones = {(_Float16)1.f, (_Float16)1.f, (_Float16)1.f, (_Float16)1.f,
                     (_Float16)1.f, (_Float16)1.f, (_Float16)1.f, (_Float16)1.f};

    const int NW = 2048 * 4;
    int n = blockIdx.x * 4 + wv;       // NW < NN so always valid
    int cP   = __builtin_amdgcn_readfirstlane(cnt[n]);
    int base = __builtin_amdgcn_readfirstlane(offs[n]);
    int deg  = cP & 0xffff;
    int sgm  = deg - 2 * ((int)((unsigned)cP >> 16));
    int ev   = adj[base + lane];
    float hn = hcur[(size_t)n * 64 + lane];
    float hA0, hA1, hA2, hA3, hA4, hA5, hA6, hA7;
    float hA8, hA9, hA10, hA11, hA12, hA13, hA14, hA15;
    float hB0, hB1, hB2, hB3, hB4, hB5, hB6, hB7;
    float hB8, hB9, hB10, hB11, hB12, hB13, hB14, hB15;
    G16(hA, ev, 0);

    for (;;) {
        const int nxt = n + NW;
        const bool morenode = nxt < NN;
        int baseN = 0, cN = 0, evN = 0;
        float hnN = 0.f;
        if (morenode) {
            baseN = __builtin_amdgcn_readfirstlane(offs[nxt]);
            cN    = __builtin_amdgcn_readfirstlane(cnt[nxt]);
            evN   = adj[baseN + lane];
            hnN   = hcur[(size_t)nxt * 64 + lane];
        }
        TileAcc A = {0.f, 0.f, 0.f, 0.f, 0.f};

        if (deg > 0) {
            int cbase = 0;
            for (;;) {
                int nE = deg - cbase;
                if (nE > 64) nE = 64;
                const bool morechunk = (cbase + 64 < deg);
                int evB = 0;
                if (morechunk) evB = adj[base + cbase + 64 + lane];

                if (nE == 64) {
                    G16(hB, ev, 16);
                    tile16<false>(A, hn, 0, HV(hA), wp, trv, ones);
                    G16(hA, ev, 32);
                    tile16<false>(A, hn, 0, HV(hB), wp, trv, ones);
                    G16(hB, ev, 48);
                    tile16<false>(A, hn, 0, HV(hA), wp, trv, ones);
                    NEXTPREF(hA);
                    tile16<false>(A, hn, 0, HV(hB), wp, trv, ones);
                } else {
                    const int nt = (nE + 15) >> 4;
                    if (nt > 1) { G16(hB, ev, 16); } else { NEXTPREF(hB); }
                    tile16<true>(A, hn, nE, HV(hA), wp, trv, ones);
                    if (nt > 1) {
                        if (nt > 2) { G16(hA, ev, 32); } else { NEXTPREF(hA); }
                        tile16<true>(A, hn, nE - 16, HV(hB), wp, trv, ones);
                        if (nt > 2) {
                            if (nt > 3) { G16(hB, ev, 48); } else { NEXTPREF(hB); }
                            tile16<true>(A, hn, nE - 32, HV(hA), wp, trv, ones);
                            if (nt > 3) {
                                NEXTPREF(hA);
                                tile16<true>(A, hn, nE - 48, HV(hB), wp, trv, ones);
                            }
                        }
                    }
                    if (nt & 1) {
                        hA0 = hB0;  hA1 = hB1;  hA2 = hB2;  hA3 = hB3;
                        hA4 = hB4;  hA5 = hB5;  hA6 = hB6;  hA7 = hB7;
                        hA8 = hB8;  hA9 = hB9;  hA10 = hB10; hA11 = hB11;
                        hA12 = hB12; hA13 = hB13; hA14 = hB14; hA15 = hB15;
                    }
                }
                if (!morechunk) break;
                ev = evB;
                cbase += 64;
            }
        } else {
            if (morenode) { G16(hA, evN, 0); }
        }

        // ---- epilogue: combine per-lane cs partials (row-uniform) once
        float scp = A.sc;
        asm volatile(
            "s_nop 1\n\t"
            "v_add_f32_dpp %0, %0, %0 row_bcast:15 row_mask:0xa bank_mask:0xf bound_ctrl:0\n\t"
            "s_nop 1\n\t"
            "v_add_f32_dpp %0, %0, %0 row_bcast:31 row_mask:0xc bank_mask:0xf bound_ctrl:0"
            : "+v"(scp));
        const float accM = ((A.a0 + A.a1) + (A.a2 + A.a3)) - rl63(scp);
        const float nfn = nf[n];
        const float av  = nfn * __builtin_fmaf(g, accM, b * (float)sgm);

        float p = 0.f;
        const int avi = __float_as_int(av);
#pragma unroll
        for (int k = 0; k < 64; ++k) {
            float ak = __int_as_float(RL(avi, k));
            p = __builtin_fmaf(ak, (float)Gs[k * 64 + lane], p);
        }

        float yprev = 0.f, sprev = 0.f;
        if (!first) {
            yprev = y[n * 64 + lane];
            sprev = s[n * 64 + lane];
        }
        const float yv = -ALPHA * p + (1.0f - ALPHA) * yprev;
        y[n * 64 + lane] = yv;
        s[n * 64 + lane] = (1.0f - ALPHA) * sprev + av;
        if (!last) hnxt[n * 64 + lane] = KTANH * (nfn * (yv + xU[n * 64 + lane]));

        if (!morenode) break;
        n = nxt; base = baseN;
        deg = cN & 0xffff;
        sgm = deg - 2 * ((int)((unsigned)cN >> 16));
        ev = evN; hn = hnN;
    }
#undef GATH
#undef RL
}

// ---------------------------------------------------------------------------
// final: z = -alpha*(s@W) ; zf = nf*z + xh ; out = zf@Wlast^T + blast
// ---------------------------------------------------------------------------
__global__ __launch_bounds__(256) void final_out(
        const float* __restrict__ s, const float* __restrict__ xh,
        const float* __restrict__ nf, const float* __restrict__ W,
        const float* __restrict__ Wlast, const float* __restrict__ blast,
        float* __restrict__ out) {
    __shared__ float Ws[64 * 64];
    __shared__ float WlT[64 * OUTC];
    __shared__ float blS[OUTC];
    __shared__ float ss[4][64];
    __shared__ float zfs[4][64];
    for (int t = threadIdx.x; t < 64 * 64; t += 256) Ws[t] = W[t];
    for (int t = threadIdx.x; t < OUTC * 64; t += 256) {
        int o = t >> 6, j = t & 63;
        WlT[j * OUTC + o] = Wlast[t];
    }
    if (threadIdx.x < OUTC) blS[threadIdx.x] = blast[threadIdx.x];
    __syncthreads();
    int lane = threadIdx.x & 63, wv = threadIdx.x >> 6;
    for (int n0 = blockIdx.x * 4; n0 < NN; n0 += gridDim.x * 4) {
        int n = n0 + wv;
        if (n < NN) ss[wv][lane] = s[n * 64 + lane];
        __syncthreads();
        if (n < NN) {
            float z = 0.f;
#pragma unroll 8
            for (int k = 0; k < 64; ++k) z += ss[wv][k] * Ws[k * 64 + lane];
            z *= -ALPHA;
            zfs[wv][lane] = nf[n] * z + xh[n * 64 + lane];
        }
        __syncthreads();
        if (n < NN && lane < OUTC) {
            float acc = blS[lane];
#pragma unroll 8
            for (int j = 0; j < 64; ++j) acc += zfs[wv][j] * WlT[j * OUTC + lane];
            out[n * OUTC + lane] = acc;
        }
        __syncthreads();
    }
}

// ---------------------------------------------------------------------------
extern "C" void kernel_launch(void* const* d_in, const int* in_sizes, int n_in,
                              void* d_out, int out_size, void* d_ws, size_t ws_size,
                              hipStream_t stream) {
    const float* x     = (const float*)d_in[0];
    const int*   ei    = (const int*)  d_in[1];
    const float* nf    = (const float*)d_in[2];
    const float* We    = (const float*)d_in[3];
    const float* be    = (const float*)d_in[4];
    const float* W     = (const float*)d_in[5];
    const float* U     = (const float*)d_in[6];
    const float* bU    = (const float*)d_in[7];
    const float* gamma = (const float*)d_in[8];
    const float* beta  = (const float*)d_in[9];
    const float* Wlast = (const float*)d_in[10];
    const float* blast = (const float*)d_in[11];
    float* out = (float*)d_out;

    char* ws = (char*)d_ws;
    size_t off = 0;
    const size_t NH = (size_t)NN * HH * sizeof(float);
    int*   adj    = (int*)(ws + off);            off += (size_t)2 * EE * sizeof(int) + 256;
    unsigned short* rank16 = (unsigned short*)(ws + off);
                                                 off += (size_t)2 * EE * sizeof(unsigned short);
    int*   offs   = (int*)(ws + off);            off += (size_t)NN * sizeof(int);
    int*   cnt    = (int*)(ws + off);            off += (size_t)NN * sizeof(int);
    int*   bsum   = (int*)(ws + off);            off += 256 * sizeof(int);
    float* xh     = (float*)(ws + off);          off += NH;
    float* xU     = (float*)(ws + off);          off += NH;
    float* h0     = (float*)(ws + off);          off += NH;
    float* h1     = (float*)(ws + off);          off += NH;
    float* y      = (float*)(ws + off);          off += NH;
    float* s      = (float*)(ws + off);          off += NH;
    _Float16* G   = (_Float16*)(ws + off);       off += (size_t)HH * HH * sizeof(_Float16) + 256;

    (void)hipMemsetAsync(cnt, 0, (size_t)NN * sizeof(int), stream);
    // y/s zero-init folded into fused_step (first=1)

    csr_count<<<(2 * EE + 255) / 256, 256, 0, stream>>>(ei, cnt, rank16);
    scanA<<<NB_SCAN, 256, 0, stream>>>(cnt, offs, bsum);
    scanB<<<1, 256, 0, stream>>>(bsum);
    scanC<<<NB_SCAN, 256, 0, stream>>>(offs, bsum);
    csr_fill<<<(2 * EE + 255) / 256, 256, 0, stream>>>(ei, offs, rank16, adj);

    make_G<<<16, 256, 0, stream>>>(W, G);
    extractor<<<2048, 256, 0, stream>>>(x, nf, We, be, U, bU, xh, xU, h0);

    float* hc = h0;
    float* hn = h1;
    for (int t = 0; t < 4; ++t) {
        fused_step<<<2048, 256, 0, stream>>>(adj, offs, cnt, hc, hn, nf,
                                             gamma, beta, G, xU, y, s,
                                             t == 0, t == 3);
        float* tmp = hc; hc = hn; hn = tmp;
    }
    final_out<<<2048, 256, 0, stream>>>(s, xh, nf, W, Wlast, blast, out);
}